// Round 2
// baseline (2893.737 us; speedup 1.0000x reference)
//
#include <hip/hip_runtime.h>
#include <hip/hip_bf16.h>

#define N_CRYST 256
#define ATOMS_PER 64
#define N_ATOMS (N_CRYST * ATOMS_PER)   // 16384
#define N_EDGES (N_ATOMS * 20)          // 327680
#define HID 128
#define LAT 256
#define NRAD 128
#define NBLOCK 3
#define MAXZ 100
#define CUTOFF 6.0f
#define PI_F 3.14159265358979323846f
#define EPB 8                            // edges per block in fused edge kernel

__device__ __forceinline__ float silu(float x) {
    return x / (1.0f + expf(-x));
}

// ---- zero-fill (capture-safe, no memset dependence) ----
__global__ void k_zero(float* __restrict__ p, int n) {
    int i = blockIdx.x * blockDim.x + threadIdx.x;
    if (i < n) p[i] = 0.0f;
}

// ---- K0: lattice matrices ----
__global__ void k_latt(const float* __restrict__ lengths,
                       const float* __restrict__ angles,
                       float* __restrict__ latt) {
    int c = blockIdx.x * blockDim.x + threadIdx.x;
    if (c >= N_CRYST) return;
    float a  = lengths[c * 3 + 0];
    float b  = lengths[c * 3 + 1];
    float cc = lengths[c * 3 + 2];
    float al = angles[c * 3 + 0] * (PI_F / 180.0f);
    float be = angles[c * 3 + 1] * (PI_F / 180.0f);
    float ga = angles[c * 3 + 2] * (PI_F / 180.0f);
    float cos_a = cosf(al), cos_b = cosf(be), cos_g = cosf(ga);
    float sin_a = sinf(al), sin_b = sinf(be);
    float val = (cos_a * cos_b - cos_g) / (sin_a * sin_b);
    val = fminf(1.0f, fmaxf(-1.0f, val));
    float gs = acosf(val);
    float* L = latt + c * 9;
    L[0] = a * sin_b;              L[1] = 0.0f;                  L[2] = a * cos_b;
    L[3] = -b * sin_a * cosf(gs);  L[4] = b * sin_a * sinf(gs);  L[5] = b * cos_a;
    L[6] = 0.0f;                   L[7] = 0.0f;                  L[8] = cc;
}

// ---- K1: cartesian coordinates ----
__global__ void k_cart(const float* __restrict__ frac,
                       const float* __restrict__ latt,
                       float* __restrict__ cart) {
    int n = blockIdx.x * blockDim.x + threadIdx.x;
    if (n >= N_ATOMS) return;
    int b = n / ATOMS_PER;
    const float* L = latt + b * 9;
    float f0 = frac[n * 3 + 0], f1 = frac[n * 3 + 1], f2 = frac[n * 3 + 2];
    cart[n * 3 + 0] = f0 * L[0] + f1 * L[3] + f2 * L[6];
    cart[n * 3 + 1] = f0 * L[1] + f1 * L[4] + f2 * L[7];
    cart[n * 3 + 2] = f0 * L[2] + f1 * L[5] + f2 * L[8];
}

// ---- K2: h0 = silu(concat(atom_emb[type], z[batch]) @ W_in + b_in) ----
__global__ void k_h(const int* __restrict__ types,
                    const float* __restrict__ z,
                    const float* __restrict__ atom_emb,
                    const float* __restrict__ W_in,
                    const float* __restrict__ b_in,
                    float* __restrict__ h) {
    int n = blockIdx.x;
    int t = threadIdx.x;  // 0..127
    __shared__ float row[HID + LAT];  // 384
    int type = types[n];
    int b = n / ATOMS_PER;
    row[t]             = atom_emb[type * HID + t];
    row[HID + t]       = z[b * LAT + t];
    row[HID + 128 + t] = z[b * LAT + 128 + t];
    __syncthreads();
    float acc = b_in[t];
#pragma unroll 8
    for (int k = 0; k < HID + LAT; k++) acc += row[k] * W_in[k * HID + t];
    h[n * HID + t] = silu(acc);
}

// ---- Fused edge kernel: geometry+rbf -> rbf_h -> m0 -> 3 msg blocks -> force ----
// 128 threads, EPB edges per block. m and rbf_h never touch HBM.
__global__ __launch_bounds__(128)
void k_edges(const int* __restrict__ edge_index,
             const float* __restrict__ cart,
             const float* __restrict__ h,
             const float* __restrict__ W_rbf,
             const float* __restrict__ W_edge,
             const float* __restrict__ b_edge,
             const float* __restrict__ W_msg,
             const float* __restrict__ b_msg,
             const float* __restrict__ W_gate,
             const float* __restrict__ W_force,
             float* __restrict__ agg,    // [NBLOCK][N_ATOMS][HID]
             float* __restrict__ outF)   // [N_ATOMS][3]
{
    int t = threadIdx.x;
    int e0 = blockIdx.x * EPB;

    __shared__ float rows[EPB][3 * HID];   // [h_src | h_dst | rbf_h]  12 KB
    __shared__ float mrow[EPB][HID];       // running m                 4 KB
    __shared__ float rbf[EPB][NRAD];       // radial basis              4 KB
    __shared__ float unitS[EPB][3];
    __shared__ int   dstS[EPB];

    int src8[EPB], dst8[EPB];
#pragma unroll
    for (int e = 0; e < EPB; e++) {
        src8[e] = edge_index[e0 + e];
        dst8[e] = edge_index[N_EDGES + e0 + e];
    }

    // Phase A: geometry + rbf (every thread computes d redundantly; cart reads broadcast)
    const float inv2w2 = 1.0f / (2.0f * (CUTOFF / NRAD) * (CUTOFF / NRAD));
#pragma unroll
    for (int e = 0; e < EPB; e++) {
        float vx = cart[dst8[e] * 3 + 0] - cart[src8[e] * 3 + 0];
        float vy = cart[dst8[e] * 3 + 1] - cart[src8[e] * 3 + 1];
        float vz = cart[dst8[e] * 3 + 2] - cart[src8[e] * 3 + 2];
        float d = sqrtf(vx * vx + vy * vy + vz * vz) + 1e-8f;
        if (t == 0) {
            float di = 1.0f / d;
            unitS[e][0] = vx * di; unitS[e][1] = vy * di; unitS[e][2] = vz * di;
            dstS[e] = dst8[e];
        }
        float x = fminf(1.0f, fmaxf(0.0f, d * (1.0f / CUTOFF)));
        float env = 0.5f * (cosf(PI_F * x) + 1.0f);
        float center = (float)t * (CUTOFF / (NRAD - 1));
        float diff = d - center;
        rbf[e][t] = expf(-diff * diff * inv2w2) * env;
    }
    __syncthreads();

    // Phase B: rbf_h = rbf @ W_rbf   (thread t owns output column t, 8 edges)
    float acc[EPB];
#pragma unroll
    for (int e = 0; e < EPB; e++) acc[e] = 0.0f;
#pragma unroll 4
    for (int k = 0; k < NRAD; k++) {
        float w = W_rbf[k * HID + t];
#pragma unroll
        for (int e = 0; e < EPB; e++) acc[e] += rbf[e][k] * w;
    }
#pragma unroll
    for (int e = 0; e < EPB; e++) rows[e][2 * HID + t] = acc[e];

    // Phase C: gather h rows
#pragma unroll
    for (int e = 0; e < EPB; e++) {
        rows[e][t]       = h[src8[e] * HID + t];
        rows[e][HID + t] = h[dst8[e] * HID + t];
    }
    __syncthreads();

    // Phase D: m0 = silu(rows @ W_edge + b_edge)
    float m_reg[EPB];
    float a1[EPB];
#pragma unroll
    for (int e = 0; e < EPB; e++) a1[e] = b_edge[t];
#pragma unroll 4
    for (int k = 0; k < 3 * HID; k++) {
        float w = W_edge[k * HID + t];
#pragma unroll
        for (int e = 0; e < EPB; e++) a1[e] += rows[e][k] * w;
    }
#pragma unroll
    for (int e = 0; e < EPB; e++) { m_reg[e] = silu(a1[e]); mrow[e][t] = m_reg[e]; }
    __syncthreads();

    // Phase E: 3 message blocks
    for (int i = 0; i < NBLOCK; i++) {
        const float* Wm = W_msg  + (size_t)i * HID * HID;
        const float* Wg = W_gate + (size_t)i * HID * HID;
        float bm = b_msg[i * HID + t];
        float g[EPB];
#pragma unroll
        for (int e = 0; e < EPB; e++) { a1[e] = bm; g[e] = 0.0f; }
#pragma unroll 4
        for (int k = 0; k < HID; k++) {
            float wm = Wm[k * HID + t];
            float wg = Wg[k * HID + t];
#pragma unroll
            for (int e = 0; e < EPB; e++) {
                a1[e] += mrow[e][k] * wm;
                g[e]  += rows[e][2 * HID + k] * wg;
            }
        }
        __syncthreads();  // all reads of old mrow complete
        float* aggp = agg + (size_t)i * N_ATOMS * HID;
#pragma unroll
        for (int e = 0; e < EPB; e++) {
            float m2 = silu(a1[e]) * g[e];
            atomicAdd(&aggp[dst8[e] * HID + t], m2);
            m_reg[e] += m2;
            mrow[e][t] = m_reg[e];
        }
        __syncthreads();  // new mrow visible
    }

    // Phase F: force f_e = m_final . W_force ; outF[dst] += f_e * unit
    {
        int e    = t >> 4;    // 16 threads per edge
        int lane = t & 15;
        float partial = 0.0f;
#pragma unroll
        for (int j = 0; j < HID / 16; j++)
            partial += mrow[e][lane + 16 * j] * W_force[lane + 16 * j];
#pragma unroll
        for (int s = 8; s >= 1; s >>= 1)
            partial += __shfl_xor(partial, s, 64);
        if (lane < 3) {
            int d = dstS[e];
            atomicAdd(&outF[d * 3 + lane], partial * unitS[e][lane]);
        }
    }
}

// ---- Atom-side: h = h0 + sum_i silu(agg_i @ W_upd_i + b_upd_i); out = h @ W_atom + b ----
__global__ void k_atom(const float* __restrict__ agg,
                       const float* __restrict__ W_upd,
                       const float* __restrict__ b_upd,
                       const float* __restrict__ W_atom,
                       const float* __restrict__ b_atom,
                       const float* __restrict__ h,
                       float* __restrict__ out) {
    int n = blockIdx.x;
    int t = threadIdx.x;  // 0..127
    __shared__ float hrow[HID];
    __shared__ float arow[HID];
    hrow[t] = h[n * HID + t];
    for (int i = 0; i < NBLOCK; i++) {
        arow[t] = agg[(size_t)i * N_ATOMS * HID + n * HID + t];
        __syncthreads();
        float acc = b_upd[i * HID + t];
        const float* Wu = W_upd + (size_t)i * HID * HID;
#pragma unroll 8
        for (int k = 0; k < HID; k++) acc += arow[k] * Wu[k * HID + t];
        __syncthreads();  // all reads of arow done before next overwrite
        hrow[t] += silu(acc);
    }
    __syncthreads();
    if (t < MAXZ) {
        float acc = b_atom[t];
#pragma unroll 8
        for (int k = 0; k < HID; k++) acc += hrow[k] * W_atom[k * MAXZ + t];
        out[N_ATOMS * 3 + n * MAXZ + t] = acc;
    }
}

extern "C" void kernel_launch(void* const* d_in, const int* in_sizes, int n_in,
                              void* d_out, int out_size, void* d_ws, size_t ws_size,
                              hipStream_t stream) {
    const float* z         = (const float*)d_in[0];
    const float* frac      = (const float*)d_in[1];
    const int*   types     = (const int*)d_in[2];
    // d_in[3] = num_atoms (unused; batch = arange // ATOMS_PER)
    const float* lengths   = (const float*)d_in[4];
    const float* angles    = (const float*)d_in[5];
    const int*   edge_idx  = (const int*)d_in[6];
    const float* atom_emb  = (const float*)d_in[7];
    const float* W_in      = (const float*)d_in[8];
    const float* b_in      = (const float*)d_in[9];
    const float* W_rbf     = (const float*)d_in[10];
    const float* W_edge    = (const float*)d_in[11];
    const float* b_edge    = (const float*)d_in[12];
    const float* W_msg     = (const float*)d_in[13];
    const float* b_msg     = (const float*)d_in[14];
    const float* W_gate    = (const float*)d_in[15];
    const float* W_upd     = (const float*)d_in[16];
    const float* b_upd     = (const float*)d_in[17];
    const float* W_force   = (const float*)d_in[18];
    const float* W_atom    = (const float*)d_in[19];
    const float* b_atom    = (const float*)d_in[20];

    float* out = (float*)d_out;

    // workspace layout (floats): ~34 MB total
    float* ws = (float*)d_ws;
    size_t off = 0;
    float* latt = ws + off; off += N_CRYST * 9;
    float* cart = ws + off; off += N_ATOMS * 3;
    float* h    = ws + off; off += (size_t)N_ATOMS * HID;
    float* agg  = ws + off; off += (size_t)NBLOCK * N_ATOMS * HID;

    // zero accumulators (force output region + agg)
    {
        int nF = N_ATOMS * 3;
        k_zero<<<(nF + 255) / 256, 256, 0, stream>>>(out, nF);
        int nA = NBLOCK * N_ATOMS * HID;
        k_zero<<<(nA + 255) / 256, 256, 0, stream>>>(agg, nA);
    }

    k_latt<<<1, 256, 0, stream>>>(lengths, angles, latt);
    k_cart<<<(N_ATOMS + 255) / 256, 256, 0, stream>>>(frac, latt, cart);
    k_h<<<N_ATOMS, HID, 0, stream>>>(types, z, atom_emb, W_in, b_in, h);

    k_edges<<<N_EDGES / EPB, 128, 0, stream>>>(edge_idx, cart, h,
                                               W_rbf, W_edge, b_edge,
                                               W_msg, b_msg, W_gate, W_force,
                                               agg, out);

    k_atom<<<N_ATOMS, HID, 0, stream>>>(agg, W_upd, b_upd, W_atom, b_atom, h, out);
}

// Round 3
// 976.665 us; speedup vs baseline: 2.9629x; 2.9629x over previous
//
#include <hip/hip_runtime.h>
#include <hip/hip_bf16.h>

#define N_CRYST 256
#define ATOMS_PER 64
#define N_ATOMS (N_CRYST * ATOMS_PER)   // 16384
#define N_EDGES (N_ATOMS * 20)          // 327680
#define HID 128
#define LAT 256
#define NRAD 128
#define NBLOCK 3
#define MAXZ 100
#define CUTOFF 6.0f
#define PI_F 3.14159265358979323846f
#define ETILE 64                         // edges per block in fused edge kernel

typedef unsigned short ushort_t;
typedef __attribute__((ext_vector_type(8))) short short8;
typedef __attribute__((ext_vector_type(4))) float f32x4;

__device__ __forceinline__ float silu(float x) {
    return x / (1.0f + expf(-x));
}

__device__ __forceinline__ ushort_t f2bf(float v) {
    __hip_bfloat16 b = __float2bfloat16(v);
    return *reinterpret_cast<ushort_t*>(&b);
}
__device__ __forceinline__ float bf2f(ushort_t u) {
    __hip_bfloat16 b = *reinterpret_cast<__hip_bfloat16*>(&u);
    return __bfloat162float(b);
}

// XOR swizzle for [rows][128] bf16 LDS tiles (G4: break the 32-way column conflict)
__device__ __forceinline__ int swz(int row, int k) {
    return (row * 256 + k * 2) ^ ((row & 7) << 4);
}

__device__ __forceinline__ short8 ldsA(const ushort_t* base, int row0, int k0, int lane) {
    int row = row0 + (lane & 15);
    int k   = k0 + 8 * (lane >> 4);
    return *reinterpret_cast<const short8*>(
        reinterpret_cast<const char*>(base) + swz(row, k));
}

__device__ __forceinline__ void wr16(ushort_t* base, int row, int col, float v) {
    *reinterpret_cast<ushort_t*>(reinterpret_cast<char*>(base) + swz(row, col)) = f2bf(v);
}

__device__ __forceinline__ short8 ldB(const ushort_t* W, int col, int K, int k) {
    return *reinterpret_cast<const short8*>(W + (size_t)col * K + k);
}

__device__ __forceinline__ f32x4 MFMA(short8 a, short8 b, f32x4 c) {
    return __builtin_amdgcn_mfma_f32_16x16x32_bf16(a, b, c, 0, 0, 0);
}

// ---- zero-fill ----
__global__ void k_zero(float* __restrict__ p, int n) {
    int i = blockIdx.x * blockDim.x + threadIdx.x;
    if (i < n) p[i] = 0.0f;
}

// ---- lattice matrices ----
__global__ void k_latt(const float* __restrict__ lengths,
                       const float* __restrict__ angles,
                       float* __restrict__ latt) {
    int c = blockIdx.x * blockDim.x + threadIdx.x;
    if (c >= N_CRYST) return;
    float a  = lengths[c * 3 + 0];
    float b  = lengths[c * 3 + 1];
    float cc = lengths[c * 3 + 2];
    float al = angles[c * 3 + 0] * (PI_F / 180.0f);
    float be = angles[c * 3 + 1] * (PI_F / 180.0f);
    float ga = angles[c * 3 + 2] * (PI_F / 180.0f);
    float cos_a = cosf(al), cos_b = cosf(be), cos_g = cosf(ga);
    float sin_a = sinf(al), sin_b = sinf(be);
    float val = (cos_a * cos_b - cos_g) / (sin_a * sin_b);
    val = fminf(1.0f, fmaxf(-1.0f, val));
    float gs = acosf(val);
    float* L = latt + c * 9;
    L[0] = a * sin_b;              L[1] = 0.0f;                  L[2] = a * cos_b;
    L[3] = -b * sin_a * cosf(gs);  L[4] = b * sin_a * sinf(gs);  L[5] = b * cos_a;
    L[6] = 0.0f;                   L[7] = 0.0f;                  L[8] = cc;
}

// ---- cartesian coords ----
__global__ void k_cart(const float* __restrict__ frac,
                       const float* __restrict__ latt,
                       float* __restrict__ cart) {
    int n = blockIdx.x * blockDim.x + threadIdx.x;
    if (n >= N_ATOMS) return;
    int b = n / ATOMS_PER;
    const float* L = latt + b * 9;
    float f0 = frac[n * 3 + 0], f1 = frac[n * 3 + 1], f2 = frac[n * 3 + 2];
    cart[n * 3 + 0] = f0 * L[0] + f1 * L[3] + f2 * L[6];
    cart[n * 3 + 1] = f0 * L[1] + f1 * L[4] + f2 * L[7];
    cart[n * 3 + 2] = f0 * L[2] + f1 * L[5] + f2 * L[8];
}

// ---- weight prep: transpose + bf16 (Wt[col][k], k contiguous = B-fragment layout) ----
__global__ void k_prep(const float* __restrict__ W_rbf,   // [128][128]
                       const float* __restrict__ W_edge,  // [384][128]
                       const float* __restrict__ W_msg,   // [3][128][128]
                       const float* __restrict__ W_gate,  // [3][128][128]
                       ushort_t* __restrict__ Wt_rbf,     // [128][128]
                       ushort_t* __restrict__ Wt_edge,    // [128][384]
                       ushort_t* __restrict__ Wt_msg,     // [3][128][128]
                       ushort_t* __restrict__ Wt_gate) {
    int i = blockIdx.x * blockDim.x + threadIdx.x;  // 0..49151
    if (i < 128 * 128) {
        int c = i >> 7, k = i & 127;
        Wt_rbf[c * 128 + k] = f2bf(W_rbf[k * 128 + c]);
    }
    if (i < 128 * 384) {
        int c = i / 384, k = i % 384;
        Wt_edge[(size_t)c * 384 + k] = f2bf(W_edge[k * 128 + c]);
    }
    if (i < 3 * 128 * 128) {
        int blk = i >> 14, r = i & 16383;
        int c = r >> 7, k = r & 127;
        Wt_msg[blk * 16384 + c * 128 + k]  = f2bf(W_msg[blk * 16384 + k * 128 + c]);
        Wt_gate[blk * 16384 + c * 128 + k] = f2bf(W_gate[blk * 16384 + k * 128 + c]);
    }
}

// ---- h0 = silu(concat(atom_emb[type], z[batch]) @ W_in + b_in), stored bf16 ----
__global__ void k_h(const int* __restrict__ types,
                    const float* __restrict__ z,
                    const float* __restrict__ atom_emb,
                    const float* __restrict__ W_in,
                    const float* __restrict__ b_in,
                    ushort_t* __restrict__ h_bf) {
    int n = blockIdx.x;
    int t = threadIdx.x;  // 0..127
    __shared__ float row[HID + LAT];
    int type = types[n];
    int b = n / ATOMS_PER;
    row[t]             = atom_emb[type * HID + t];
    row[HID + t]       = z[b * LAT + t];
    row[HID + 128 + t] = z[b * LAT + 128 + t];
    __syncthreads();
    float acc = b_in[t];
#pragma unroll 8
    for (int k = 0; k < HID + LAT; k++) acc += row[k] * W_in[k * HID + t];
    h_bf[n * HID + t] = f2bf(silu(acc));
}

// ---- Fused edge kernel (MFMA): geometry+rbf -> rbf_h -> m0 -> 3 msg blocks -> force ----
// 256 threads = 4 waves; 64 edges/block; wave w owns output cols [32w, 32w+32).
__global__ __launch_bounds__(256)
void k_edges(const int* __restrict__ edge_index,
             const float* __restrict__ cart,
             const ushort_t* __restrict__ h_bf,
             const ushort_t* __restrict__ Wt_rbf,
             const ushort_t* __restrict__ Wt_edge,
             const float* __restrict__ b_edge,
             const ushort_t* __restrict__ Wt_msg,
             const float* __restrict__ b_msg,
             const ushort_t* __restrict__ Wt_gate,
             const float* __restrict__ W_force,
             float* __restrict__ agg,    // [NBLOCK][N_ATOMS][HID]
             float* __restrict__ outF)   // [N_ATOMS][3]
{
    __shared__ ushort_t sm_rbf [ETILE * HID];   // 16 KB, swizzled
    __shared__ ushort_t sm_rbfh[ETILE * HID];   // 16 KB, swizzled
    __shared__ ushort_t sm_m   [ETILE * HID];   // 16 KB, swizzled
    __shared__ int   sm_src[ETILE], sm_dst[ETILE];
    __shared__ float sm_unit[ETILE][3];
    __shared__ float sm_d[ETILE];
    __shared__ float sm_f[ETILE];

    const int t    = threadIdx.x;
    const int lane = t & 63;
    const int wave = t >> 6;
    const int l15  = lane & 15;
    const int lk8  = 8 * (lane >> 4);
    const int colw = wave * 32;
    const int e0   = blockIdx.x * ETILE;

    // ---- Phase A0: per-edge geometry ----
    if (t < ETILE) {
        int e = t;
        int s = edge_index[e0 + e];
        int d = edge_index[N_EDGES + e0 + e];
        sm_src[e] = s; sm_dst[e] = d;
        float vx = cart[d * 3 + 0] - cart[s * 3 + 0];
        float vy = cart[d * 3 + 1] - cart[s * 3 + 1];
        float vz = cart[d * 3 + 2] - cart[s * 3 + 2];
        float dist = sqrtf(vx * vx + vy * vy + vz * vz) + 1e-8f;
        sm_d[e] = dist;
        float di = 1.0f / dist;
        sm_unit[e][0] = vx * di; sm_unit[e][1] = vy * di; sm_unit[e][2] = vz * di;
        sm_f[e] = 0.0f;
    }
    __syncthreads();

    // ---- Phase A1: rbf -> sm_rbf (bf16, swizzled) ----
    {
        const float inv2w2 = 1.0f / (2.0f * (CUTOFF / NRAD) * (CUTOFF / NRAD));
        const float cstep = CUTOFF / (NRAD - 1);
#pragma unroll
        for (int it = 0; it < 16; it++) {
            int idx = it * 256 + t;          // 64 edges x 64 center-pairs
            int e = idx >> 6;
            int c = (idx & 63) * 2;
            float dist = sm_d[e];
            float x = fminf(1.0f, fmaxf(0.0f, dist * (1.0f / CUTOFF)));
            float env = 0.5f * (cosf(PI_F * x) + 1.0f);
            float d0 = dist - c * cstep;
            float d1 = dist - (c + 1) * cstep;
            float r0 = expf(-d0 * d0 * inv2w2) * env;
            float r1 = expf(-d1 * d1 * inv2w2) * env;
            unsigned int pk = ((unsigned int)f2bf(r1) << 16) | f2bf(r0);
            *reinterpret_cast<unsigned int*>(
                reinterpret_cast<char*>(sm_rbf) + swz(e, c)) = pk;
        }
    }
    __syncthreads();

    // ---- GEMM1: rbf_h = rbf @ W_rbf ----
    {
        short8 B[2][4];
#pragma unroll
        for (int nt = 0; nt < 2; nt++)
#pragma unroll
            for (int ks = 0; ks < 4; ks++)
                B[nt][ks] = ldB(Wt_rbf, colw + nt * 16 + l15, 128, ks * 32 + lk8);
#pragma unroll
        for (int at = 0; at < 4; at++) {
            f32x4 a0 = {0.f, 0.f, 0.f, 0.f}, a1 = {0.f, 0.f, 0.f, 0.f};
#pragma unroll
            for (int ks = 0; ks < 4; ks++) {
                short8 A = ldsA(sm_rbf, at * 16, ks * 32, lane);
                a0 = MFMA(A, B[0][ks], a0);
                a1 = MFMA(A, B[1][ks], a1);
            }
#pragma unroll
            for (int r = 0; r < 4; r++) {
                int row = at * 16 + (lane >> 4) * 4 + r;
                wr16(sm_rbfh, row, colw + l15,      a0[r]);
                wr16(sm_rbfh, row, colw + 16 + l15, a1[r]);
            }
        }
    }
    __syncthreads();

    // per-lane row indices for A-gathers and C-rows
    int srcr[4], dstr[4];
#pragma unroll
    for (int at = 0; at < 4; at++) {
        srcr[at] = sm_src[at * 16 + l15];
        dstr[at] = sm_dst[at * 16 + l15];
    }
    int dstC[4][4];
#pragma unroll
    for (int at = 0; at < 4; at++)
#pragma unroll
        for (int r = 0; r < 4; r++)
            dstC[at][r] = sm_dst[at * 16 + (lane >> 4) * 4 + r];

    // ---- GEMM2: m0 = silu([h_src|h_dst|rbf_h] @ W_edge + b_edge) ----
    float m_acc[4][2][4];   // [at][nt][r] running m, f32, this wave's cols
    {
        f32x4 am[4][2];
#pragma unroll
        for (int at = 0; at < 4; at++)
#pragma unroll
            for (int nt = 0; nt < 2; nt++)
                am[at][nt] = (f32x4){0.f, 0.f, 0.f, 0.f};
#pragma unroll
        for (int seg = 0; seg < 3; seg++) {
#pragma unroll
            for (int ks = 0; ks < 4; ks++) {
                int kg = seg * 128 + ks * 32 + lk8;
                short8 B0 = ldB(Wt_edge, colw + l15,      384, kg);
                short8 B1 = ldB(Wt_edge, colw + 16 + l15, 384, kg);
#pragma unroll
                for (int at = 0; at < 4; at++) {
                    short8 A;
                    if (seg == 0)
                        A = *reinterpret_cast<const short8*>(
                            h_bf + (size_t)srcr[at] * HID + ks * 32 + lk8);
                    else if (seg == 1)
                        A = *reinterpret_cast<const short8*>(
                            h_bf + (size_t)dstr[at] * HID + ks * 32 + lk8);
                    else
                        A = ldsA(sm_rbfh, at * 16, ks * 32, lane);
                    am[at][0] = MFMA(A, B0, am[at][0]);
                    am[at][1] = MFMA(A, B1, am[at][1]);
                }
            }
        }
        float be0 = b_edge[colw + l15];
        float be1 = b_edge[colw + 16 + l15];
#pragma unroll
        for (int at = 0; at < 4; at++)
#pragma unroll
            for (int r = 0; r < 4; r++) {
                m_acc[at][0][r] = silu(am[at][0][r] + be0);
                m_acc[at][1][r] = silu(am[at][1][r] + be1);
            }
        // publish m as bf16 (no barrier needed before writes: each wave writes
        // only its own col slice, and sm_m hasn't been read yet)
#pragma unroll
        for (int at = 0; at < 4; at++)
#pragma unroll
            for (int r = 0; r < 4; r++) {
                int row = at * 16 + (lane >> 4) * 4 + r;
                wr16(sm_m, row, colw + l15,      m_acc[at][0][r]);
                wr16(sm_m, row, colw + 16 + l15, m_acc[at][1][r]);
            }
    }

    // ---- message blocks ----
    for (int i = 0; i < NBLOCK; i++) {
        __syncthreads();   // sm_m writes visible to all waves
        const ushort_t* Wm = Wt_msg  + i * 16384;
        const ushort_t* Wg = Wt_gate + i * 16384;
        float* aggp = agg + (size_t)i * N_ATOMS * HID;
#pragma unroll
        for (int nt = 0; nt < 2; nt++) {
            int col = colw + nt * 16 + l15;
            float bm = b_msg[i * HID + col];
            f32x4 am_[4], ag_[4];
#pragma unroll
            for (int at = 0; at < 4; at++) {
                am_[at] = (f32x4){0.f, 0.f, 0.f, 0.f};
                ag_[at] = (f32x4){0.f, 0.f, 0.f, 0.f};
            }
#pragma unroll
            for (int ks = 0; ks < 4; ks++) {
                short8 Bm = ldB(Wm, col, 128, ks * 32 + lk8);
                short8 Bg = ldB(Wg, col, 128, ks * 32 + lk8);
#pragma unroll
                for (int at = 0; at < 4; at++) {
                    short8 Am = ldsA(sm_m,    at * 16, ks * 32, lane);
                    short8 Ag = ldsA(sm_rbfh, at * 16, ks * 32, lane);
                    am_[at] = MFMA(Am, Bm, am_[at]);
                    ag_[at] = MFMA(Ag, Bg, ag_[at]);
                }
            }
#pragma unroll
            for (int at = 0; at < 4; at++)
#pragma unroll
                for (int r = 0; r < 4; r++) {
                    float m2 = silu(am_[at][r] + bm) * ag_[at][r];
                    atomicAdd(&aggp[(size_t)dstC[at][r] * HID + col], m2);
                    m_acc[at][nt][r] += m2;
                }
        }
        __syncthreads();   // all reads of old sm_m complete
        if (i < NBLOCK - 1) {
#pragma unroll
            for (int at = 0; at < 4; at++)
#pragma unroll
                for (int r = 0; r < 4; r++) {
                    int row = at * 16 + (lane >> 4) * 4 + r;
                    wr16(sm_m, row, colw + l15,      m_acc[at][0][r]);
                    wr16(sm_m, row, colw + 16 + l15, m_acc[at][1][r]);
                }
        }
    }

    // ---- force: f_e = m . W_force ; outF[dst] += f_e * unit ----
    {
        float wf0 = W_force[colw + l15];
        float wf1 = W_force[colw + 16 + l15];
#pragma unroll
        for (int at = 0; at < 4; at++)
#pragma unroll
            for (int r = 0; r < 4; r++) {
                float part = m_acc[at][0][r] * wf0 + m_acc[at][1][r] * wf1;
                part += __shfl_xor(part, 1, 64);
                part += __shfl_xor(part, 2, 64);
                part += __shfl_xor(part, 4, 64);
                part += __shfl_xor(part, 8, 64);
                if (l15 == 0)
                    atomicAdd(&sm_f[at * 16 + (lane >> 4) * 4 + r], part);
            }
        __syncthreads();
        if (t < ETILE) {
            int e = t;
            float f = sm_f[e];
            int d = sm_dst[e];
#pragma unroll
            for (int k = 0; k < 3; k++)
                atomicAdd(&outF[d * 3 + k], f * sm_unit[e][k]);
        }
    }
}

// ---- Atom-side: h = h0 + sum_i silu(agg_i @ W_upd_i + b_upd_i); out = h @ W_atom + b ----
__global__ void k_atom(const float* __restrict__ agg,
                       const float* __restrict__ W_upd,
                       const float* __restrict__ b_upd,
                       const float* __restrict__ W_atom,
                       const float* __restrict__ b_atom,
                       const ushort_t* __restrict__ h_bf,
                       float* __restrict__ out) {
    int n = blockIdx.x;
    int t = threadIdx.x;  // 0..127
    __shared__ float hrow[HID];
    __shared__ float arow[HID];
    hrow[t] = bf2f(h_bf[n * HID + t]);
    for (int i = 0; i < NBLOCK; i++) {
        arow[t] = agg[(size_t)i * N_ATOMS * HID + n * HID + t];
        __syncthreads();
        float acc = b_upd[i * HID + t];
        const float* Wu = W_upd + (size_t)i * HID * HID;
#pragma unroll 8
        for (int k = 0; k < HID; k++) acc += arow[k] * Wu[k * HID + t];
        __syncthreads();
        hrow[t] += silu(acc);
    }
    __syncthreads();
    if (t < MAXZ) {
        float acc = b_atom[t];
#pragma unroll 8
        for (int k = 0; k < HID; k++) acc += hrow[k] * W_atom[k * MAXZ + t];
        out[N_ATOMS * 3 + n * MAXZ + t] = acc;
    }
}

extern "C" void kernel_launch(void* const* d_in, const int* in_sizes, int n_in,
                              void* d_out, int out_size, void* d_ws, size_t ws_size,
                              hipStream_t stream) {
    const float* z         = (const float*)d_in[0];
    const float* frac      = (const float*)d_in[1];
    const int*   types     = (const int*)d_in[2];
    const float* lengths   = (const float*)d_in[4];
    const float* angles    = (const float*)d_in[5];
    const int*   edge_idx  = (const int*)d_in[6];
    const float* atom_emb  = (const float*)d_in[7];
    const float* W_in      = (const float*)d_in[8];
    const float* b_in      = (const float*)d_in[9];
    const float* W_rbf     = (const float*)d_in[10];
    const float* W_edge    = (const float*)d_in[11];
    const float* b_edge    = (const float*)d_in[12];
    const float* W_msg     = (const float*)d_in[13];
    const float* b_msg     = (const float*)d_in[14];
    const float* W_gate    = (const float*)d_in[15];
    const float* W_upd     = (const float*)d_in[16];
    const float* b_upd     = (const float*)d_in[17];
    const float* W_force   = (const float*)d_in[18];
    const float* W_atom    = (const float*)d_in[19];
    const float* b_atom    = (const float*)d_in[20];

    float* out = (float*)d_out;

    // workspace layout: f32 region, then bf16 region (16B-aligned offsets)
    float* ws = (float*)d_ws;
    size_t off = 0;
    float* latt = ws + off; off += N_CRYST * 9;         // 2304
    float* cart = ws + off; off += (size_t)N_ATOMS * 3; // 49152
    float* agg  = ws + off; off += (size_t)NBLOCK * N_ATOMS * HID;  // 6.29M
    off = (off + 7) & ~(size_t)7;
    ushort_t* ub = (ushort_t*)(ws + off);
    size_t uoff = 0;
    ushort_t* h_bf    = ub + uoff; uoff += (size_t)N_ATOMS * HID;   // 2.10M
    ushort_t* Wt_rbf  = ub + uoff; uoff += 128 * 128;
    ushort_t* Wt_edge = ub + uoff; uoff += 128 * 384;
    ushort_t* Wt_msg  = ub + uoff; uoff += 3 * 128 * 128;
    ushort_t* Wt_gate = ub + uoff; uoff += 3 * 128 * 128;

    // zero accumulators
    {
        int nF = N_ATOMS * 3;
        k_zero<<<(nF + 255) / 256, 256, 0, stream>>>(out, nF);
        int nA = NBLOCK * N_ATOMS * HID;
        k_zero<<<(nA + 255) / 256, 256, 0, stream>>>(agg, nA);
    }

    k_latt<<<1, 256, 0, stream>>>(lengths, angles, latt);
    k_cart<<<(N_ATOMS + 255) / 256, 256, 0, stream>>>(frac, latt, cart);
    k_prep<<<192, 256, 0, stream>>>(W_rbf, W_edge, W_msg, W_gate,
                                    Wt_rbf, Wt_edge, Wt_msg, Wt_gate);
    k_h<<<N_ATOMS, HID, 0, stream>>>(types, z, atom_emb, W_in, b_in, h_bf);

    k_edges<<<N_EDGES / ETILE, 256, 0, stream>>>(edge_idx, cart, h_bf,
                                                 Wt_rbf, Wt_edge, b_edge,
                                                 Wt_msg, b_msg, Wt_gate, W_force,
                                                 agg, out);

    k_atom<<<N_ATOMS, HID, 0, stream>>>(agg, W_upd, b_upd, W_atom, b_atom, h_bf, out);
}

// Round 4
// 733.238 us; speedup vs baseline: 3.9465x; 1.3320x over previous
//
#include <hip/hip_runtime.h>
#include <hip/hip_bf16.h>

#define N_CRYST 256
#define ATOMS_PER 64
#define N_ATOMS (N_CRYST * ATOMS_PER)   // 16384
#define N_EDGES (N_ATOMS * 20)          // 327680
#define HID 128
#define LAT 256
#define NRAD 128
#define NBLOCK 3
#define MAXZ 100
#define CUTOFF 6.0f
#define PI_F 3.14159265358979323846f
#define ETILE 64                         // edges per block in fused edge kernel

typedef unsigned short ushort_t;
typedef __attribute__((ext_vector_type(8))) short short8;
typedef __attribute__((ext_vector_type(4))) float f32x4;

__device__ __forceinline__ float silu(float x) {
    return x / (1.0f + expf(-x));
}

__device__ __forceinline__ ushort_t f2bf(float v) {
    __hip_bfloat16 b = __float2bfloat16(v);
    return *reinterpret_cast<ushort_t*>(&b);
}
__device__ __forceinline__ float bf2f(ushort_t u) {
    __hip_bfloat16 b = *reinterpret_cast<__hip_bfloat16*>(&u);
    return __bfloat162float(b);
}

// XOR swizzle for [rows][128] bf16 LDS tiles (G4: break the 32-way column conflict)
__device__ __forceinline__ int swz(int row, int k) {
    return (row * 256 + k * 2) ^ ((row & 7) << 4);
}

__device__ __forceinline__ short8 ldsA(const ushort_t* base, int row0, int k0, int lane) {
    int row = row0 + (lane & 15);
    int k   = k0 + 8 * (lane >> 4);
    return *reinterpret_cast<const short8*>(
        reinterpret_cast<const char*>(base) + swz(row, k));
}

__device__ __forceinline__ void wr16(ushort_t* base, int row, int col, float v) {
    *reinterpret_cast<ushort_t*>(reinterpret_cast<char*>(base) + swz(row, col)) = f2bf(v);
}

__device__ __forceinline__ float rd16(const ushort_t* base, int row, int col) {
    return bf2f(*reinterpret_cast<const ushort_t*>(
        reinterpret_cast<const char*>(base) + swz(row, col)));
}

__device__ __forceinline__ short8 ldB(const ushort_t* W, int col, int K, int k) {
    return *reinterpret_cast<const short8*>(W + (size_t)col * K + k);
}

__device__ __forceinline__ f32x4 MFMA(short8 a, short8 b, f32x4 c) {
    return __builtin_amdgcn_mfma_f32_16x16x32_bf16(a, b, c, 0, 0, 0);
}

// ---- zero-fill ----
__global__ void k_zero(float* __restrict__ p, int n) {
    int i = blockIdx.x * blockDim.x + threadIdx.x;
    if (i < n) p[i] = 0.0f;
}
__global__ void k_zero_i(int* __restrict__ p, int n) {
    int i = blockIdx.x * blockDim.x + threadIdx.x;
    if (i < n) p[i] = 0;
}

// ---- counting sort of edges by dst: histogram ----
__global__ void k_hist(const int* __restrict__ edge_index, int* __restrict__ cnt) {
    int e = blockIdx.x * blockDim.x + threadIdx.x;
    if (e < N_EDGES) atomicAdd(&cnt[edge_index[N_EDGES + e]], 1);
}

// ---- exclusive scan of 16384 counts (single block, 256 threads) ----
__global__ void k_scan(const int* __restrict__ cnt, int* __restrict__ cursor) {
    __shared__ int partial[256];
    int t = threadIdx.x;
    int base = t * (N_ATOMS / 256);
    int s = 0;
    for (int j = 0; j < N_ATOMS / 256; j++) s += cnt[base + j];
    partial[t] = s;
    __syncthreads();
    if (t == 0) {
        int run = 0;
        for (int i = 0; i < 256; i++) { int v = partial[i]; partial[i] = run; run += v; }
    }
    __syncthreads();
    int run = partial[t];
    for (int j = 0; j < N_ATOMS / 256; j++) {
        cursor[base + j] = run;
        run += cnt[base + j];
    }
}

// ---- scatter edge ids into dst-sorted order ----
__global__ void k_scatter(const int* __restrict__ edge_index,
                          int* __restrict__ cursor, int* __restrict__ perm) {
    int e = blockIdx.x * blockDim.x + threadIdx.x;
    if (e < N_EDGES) {
        int pos = atomicAdd(&cursor[edge_index[N_EDGES + e]], 1);
        perm[pos] = e;
    }
}

// ---- lattice matrices ----
__global__ void k_latt(const float* __restrict__ lengths,
                       const float* __restrict__ angles,
                       float* __restrict__ latt) {
    int c = blockIdx.x * blockDim.x + threadIdx.x;
    if (c >= N_CRYST) return;
    float a  = lengths[c * 3 + 0];
    float b  = lengths[c * 3 + 1];
    float cc = lengths[c * 3 + 2];
    float al = angles[c * 3 + 0] * (PI_F / 180.0f);
    float be = angles[c * 3 + 1] * (PI_F / 180.0f);
    float ga = angles[c * 3 + 2] * (PI_F / 180.0f);
    float cos_a = cosf(al), cos_b = cosf(be), cos_g = cosf(ga);
    float sin_a = sinf(al), sin_b = sinf(be);
    float val = (cos_a * cos_b - cos_g) / (sin_a * sin_b);
    val = fminf(1.0f, fmaxf(-1.0f, val));
    float gs = acosf(val);
    float* L = latt + c * 9;
    L[0] = a * sin_b;              L[1] = 0.0f;                  L[2] = a * cos_b;
    L[3] = -b * sin_a * cosf(gs);  L[4] = b * sin_a * sinf(gs);  L[5] = b * cos_a;
    L[6] = 0.0f;                   L[7] = 0.0f;                  L[8] = cc;
}

// ---- cartesian coords ----
__global__ void k_cart(const float* __restrict__ frac,
                       const float* __restrict__ latt,
                       float* __restrict__ cart) {
    int n = blockIdx.x * blockDim.x + threadIdx.x;
    if (n >= N_ATOMS) return;
    int b = n / ATOMS_PER;
    const float* L = latt + b * 9;
    float f0 = frac[n * 3 + 0], f1 = frac[n * 3 + 1], f2 = frac[n * 3 + 2];
    cart[n * 3 + 0] = f0 * L[0] + f1 * L[3] + f2 * L[6];
    cart[n * 3 + 1] = f0 * L[1] + f1 * L[4] + f2 * L[7];
    cart[n * 3 + 2] = f0 * L[2] + f1 * L[5] + f2 * L[8];
}

// ---- weight prep: transpose + bf16 (Wt[col][k], k contiguous = B-fragment layout) ----
__global__ void k_prep(const float* __restrict__ W_rbf,
                       const float* __restrict__ W_edge,
                       const float* __restrict__ W_msg,
                       const float* __restrict__ W_gate,
                       ushort_t* __restrict__ Wt_rbf,
                       ushort_t* __restrict__ Wt_edge,
                       ushort_t* __restrict__ Wt_msg,
                       ushort_t* __restrict__ Wt_gate) {
    int i = blockIdx.x * blockDim.x + threadIdx.x;
    if (i < 128 * 128) {
        int c = i >> 7, k = i & 127;
        Wt_rbf[c * 128 + k] = f2bf(W_rbf[k * 128 + c]);
    }
    if (i < 128 * 384) {
        int c = i / 384, k = i % 384;
        Wt_edge[(size_t)c * 384 + k] = f2bf(W_edge[k * 128 + c]);
    }
    if (i < 3 * 128 * 128) {
        int blk = i >> 14, r = i & 16383;
        int c = r >> 7, k = r & 127;
        Wt_msg[blk * 16384 + c * 128 + k]  = f2bf(W_msg[blk * 16384 + k * 128 + c]);
        Wt_gate[blk * 16384 + c * 128 + k] = f2bf(W_gate[blk * 16384 + k * 128 + c]);
    }
}

// ---- h0 = silu(concat(atom_emb[type], z[batch]) @ W_in + b_in), stored bf16 ----
__global__ void k_h(const int* __restrict__ types,
                    const float* __restrict__ z,
                    const float* __restrict__ atom_emb,
                    const float* __restrict__ W_in,
                    const float* __restrict__ b_in,
                    ushort_t* __restrict__ h_bf) {
    int n = blockIdx.x;
    int t = threadIdx.x;  // 0..127
    __shared__ float row[HID + LAT];
    int type = types[n];
    int b = n / ATOMS_PER;
    row[t]             = atom_emb[type * HID + t];
    row[HID + t]       = z[b * LAT + t];
    row[HID + 128 + t] = z[b * LAT + 128 + t];
    __syncthreads();
    float acc = b_in[t];
#pragma unroll 8
    for (int k = 0; k < HID + LAT; k++) acc += row[k] * W_in[k * HID + t];
    h_bf[n * HID + t] = f2bf(silu(acc));
}

// ---- Fused edge kernel (MFMA), dst-sorted edges, LDS-aggregated segment sums ----
__global__ __launch_bounds__(256)
void k_edges(const int* __restrict__ perm,
             const int* __restrict__ edge_index,
             const float* __restrict__ cart,
             const ushort_t* __restrict__ h_bf,
             const ushort_t* __restrict__ Wt_rbf,
             const ushort_t* __restrict__ Wt_edge,
             const float* __restrict__ b_edge,
             const ushort_t* __restrict__ Wt_msg,
             const float* __restrict__ b_msg,
             const ushort_t* __restrict__ Wt_gate,
             const float* __restrict__ W_force,
             float* __restrict__ agg,    // [NBLOCK][N_ATOMS][HID]
             float* __restrict__ outF)   // [N_ATOMS][3]
{
    __shared__ ushort_t sm_rbf [ETILE * HID];   // 16 KB; reused as m2 tile in msg blocks
    __shared__ ushort_t sm_rbfh[ETILE * HID];   // 16 KB
    __shared__ ushort_t sm_m   [ETILE * HID];   // 16 KB
    __shared__ int   sm_src[ETILE], sm_dst[ETILE];
    __shared__ float sm_unit[ETILE][3];
    __shared__ float sm_d[ETILE];
    __shared__ float sm_f[ETILE];

    const int t    = threadIdx.x;
    const int lane = t & 63;
    const int wave = t >> 6;
    const int l15  = lane & 15;
    const int lk8  = 8 * (lane >> 4);
    const int colw = wave * 32;
    const int e0   = blockIdx.x * ETILE;

    // ---- Phase A0: per-edge geometry (edges in dst-sorted order) ----
    if (t < ETILE) {
        int e = t;
        int eid = perm[e0 + e];
        int s = edge_index[eid];
        int d = edge_index[N_EDGES + eid];
        sm_src[e] = s; sm_dst[e] = d;
        float vx = cart[d * 3 + 0] - cart[s * 3 + 0];
        float vy = cart[d * 3 + 1] - cart[s * 3 + 1];
        float vz = cart[d * 3 + 2] - cart[s * 3 + 2];
        float dist = sqrtf(vx * vx + vy * vy + vz * vz) + 1e-8f;
        sm_d[e] = dist;
        float di = 1.0f / dist;
        sm_unit[e][0] = vx * di; sm_unit[e][1] = vy * di; sm_unit[e][2] = vz * di;
        sm_f[e] = 0.0f;
    }
    __syncthreads();

    // ---- Phase A1: rbf -> sm_rbf (bf16, swizzled) ----
    {
        const float inv2w2 = 1.0f / (2.0f * (CUTOFF / NRAD) * (CUTOFF / NRAD));
        const float cstep = CUTOFF / (NRAD - 1);
#pragma unroll
        for (int it = 0; it < 16; it++) {
            int idx = it * 256 + t;
            int e = idx >> 6;
            int c = (idx & 63) * 2;
            float dist = sm_d[e];
            float x = fminf(1.0f, fmaxf(0.0f, dist * (1.0f / CUTOFF)));
            float env = 0.5f * (cosf(PI_F * x) + 1.0f);
            float d0 = dist - c * cstep;
            float d1 = dist - (c + 1) * cstep;
            float r0 = expf(-d0 * d0 * inv2w2) * env;
            float r1 = expf(-d1 * d1 * inv2w2) * env;
            unsigned int pk = ((unsigned int)f2bf(r1) << 16) | f2bf(r0);
            *reinterpret_cast<unsigned int*>(
                reinterpret_cast<char*>(sm_rbf) + swz(e, c)) = pk;
        }
    }
    __syncthreads();

    // ---- GEMM1: rbf_h = rbf @ W_rbf ----
    {
        short8 B[2][4];
#pragma unroll
        for (int nt = 0; nt < 2; nt++)
#pragma unroll
            for (int ks = 0; ks < 4; ks++)
                B[nt][ks] = ldB(Wt_rbf, colw + nt * 16 + l15, 128, ks * 32 + lk8);
#pragma unroll
        for (int at = 0; at < 4; at++) {
            f32x4 a0 = {0.f, 0.f, 0.f, 0.f}, a1 = {0.f, 0.f, 0.f, 0.f};
#pragma unroll
            for (int ks = 0; ks < 4; ks++) {
                short8 A = ldsA(sm_rbf, at * 16, ks * 32, lane);
                a0 = MFMA(A, B[0][ks], a0);
                a1 = MFMA(A, B[1][ks], a1);
            }
#pragma unroll
            for (int r = 0; r < 4; r++) {
                int row = at * 16 + (lane >> 4) * 4 + r;
                wr16(sm_rbfh, row, colw + l15,      a0[r]);
                wr16(sm_rbfh, row, colw + 16 + l15, a1[r]);
            }
        }
    }
    __syncthreads();

    // per-lane row indices for A-gathers
    int srcr[4], dstr[4];
#pragma unroll
    for (int at = 0; at < 4; at++) {
        srcr[at] = sm_src[at * 16 + l15];
        dstr[at] = sm_dst[at * 16 + l15];
    }

    // ---- GEMM2: m0 = silu([h_src|h_dst|rbf_h] @ W_edge + b_edge) ----
    float m_acc[4][2][4];   // [at][nt][r]
    {
        f32x4 am[4][2];
#pragma unroll
        for (int at = 0; at < 4; at++)
#pragma unroll
            for (int nt = 0; nt < 2; nt++)
                am[at][nt] = (f32x4){0.f, 0.f, 0.f, 0.f};
#pragma unroll
        for (int seg = 0; seg < 3; seg++) {
#pragma unroll
            for (int ks = 0; ks < 4; ks++) {
                int kg = seg * 128 + ks * 32 + lk8;
                short8 B0 = ldB(Wt_edge, colw + l15,      384, kg);
                short8 B1 = ldB(Wt_edge, colw + 16 + l15, 384, kg);
#pragma unroll
                for (int at = 0; at < 4; at++) {
                    short8 A;
                    if (seg == 0)
                        A = *reinterpret_cast<const short8*>(
                            h_bf + (size_t)srcr[at] * HID + ks * 32 + lk8);
                    else if (seg == 1)
                        A = *reinterpret_cast<const short8*>(
                            h_bf + (size_t)dstr[at] * HID + ks * 32 + lk8);
                    else
                        A = ldsA(sm_rbfh, at * 16, ks * 32, lane);
                    am[at][0] = MFMA(A, B0, am[at][0]);
                    am[at][1] = MFMA(A, B1, am[at][1]);
                }
            }
        }
        float be0 = b_edge[colw + l15];
        float be1 = b_edge[colw + 16 + l15];
#pragma unroll
        for (int at = 0; at < 4; at++)
#pragma unroll
            for (int r = 0; r < 4; r++) {
                m_acc[at][0][r] = silu(am[at][0][r] + be0);
                m_acc[at][1][r] = silu(am[at][1][r] + be1);
            }
#pragma unroll
        for (int at = 0; at < 4; at++)
#pragma unroll
            for (int r = 0; r < 4; r++) {
                int row = at * 16 + (lane >> 4) * 4 + r;
                wr16(sm_m, row, colw + l15,      m_acc[at][0][r]);
                wr16(sm_m, row, colw + 16 + l15, m_acc[at][1][r]);
            }
    }

    // ---- message blocks: m2 -> LDS tile -> run-length-reduced atomics ----
    ushort_t* sm_m2 = sm_rbf;   // sm_rbf is dead after GEMM1
    for (int i = 0; i < NBLOCK; i++) {
        __syncthreads();   // sm_m publish visible (and prior reduction done)
        const ushort_t* Wm = Wt_msg  + i * 16384;
        const ushort_t* Wg = Wt_gate + i * 16384;
        float* aggp = agg + (size_t)i * N_ATOMS * HID;
#pragma unroll
        for (int nt = 0; nt < 2; nt++) {
            int col = colw + nt * 16 + l15;
            float bm = b_msg[i * HID + col];
            f32x4 am_[4], ag_[4];
#pragma unroll
            for (int at = 0; at < 4; at++) {
                am_[at] = (f32x4){0.f, 0.f, 0.f, 0.f};
                ag_[at] = (f32x4){0.f, 0.f, 0.f, 0.f};
            }
#pragma unroll
            for (int ks = 0; ks < 4; ks++) {
                short8 Bm = ldB(Wm, col, 128, ks * 32 + lk8);
                short8 Bg = ldB(Wg, col, 128, ks * 32 + lk8);
#pragma unroll
                for (int at = 0; at < 4; at++) {
                    short8 Am = ldsA(sm_m,    at * 16, ks * 32, lane);
                    short8 Ag = ldsA(sm_rbfh, at * 16, ks * 32, lane);
                    am_[at] = MFMA(Am, Bm, am_[at]);
                    ag_[at] = MFMA(Ag, Bg, ag_[at]);
                }
            }
#pragma unroll
            for (int at = 0; at < 4; at++)
#pragma unroll
                for (int r = 0; r < 4; r++) {
                    float m2 = silu(am_[at][r] + bm) * ag_[at][r];
                    int row = at * 16 + (lane >> 4) * 4 + r;
                    wr16(sm_m2, row, col, m2);
                    m_acc[at][nt][r] += m2;
                }
        }
        __syncthreads();   // sm_m2 complete; all reads of old sm_m done

        // run-length reduction over sorted dst rows: 256 threads = 2 half-tiles x 128 cols
        {
            int c  = t & 127;
            int r0 = (t >> 7) * 32;
            int run_dst = sm_dst[r0];
            float sum = rd16(sm_m2, r0, c);
            for (int row = r0 + 1; row < r0 + 32; row++) {
                int d = sm_dst[row];
                float v = rd16(sm_m2, row, c);
                if (d == run_dst) sum += v;
                else {
                    atomicAdd(&aggp[(size_t)run_dst * HID + c], sum);
                    run_dst = d; sum = v;
                }
            }
            atomicAdd(&aggp[(size_t)run_dst * HID + c], sum);
        }

        // publish updated m (different array than sm_m2/reduction reads)
        if (i < NBLOCK - 1) {
#pragma unroll
            for (int at = 0; at < 4; at++)
#pragma unroll
                for (int r = 0; r < 4; r++) {
                    int row = at * 16 + (lane >> 4) * 4 + r;
                    wr16(sm_m, row, colw + l15,      m_acc[at][0][r]);
                    wr16(sm_m, row, colw + 16 + l15, m_acc[at][1][r]);
                }
        }
    }

    // ---- force: f_e = m . W_force ; run-aggregated outF[dst] += f_e * unit ----
    {
        float wf0 = W_force[colw + l15];
        float wf1 = W_force[colw + 16 + l15];
#pragma unroll
        for (int at = 0; at < 4; at++)
#pragma unroll
            for (int r = 0; r < 4; r++) {
                float part = m_acc[at][0][r] * wf0 + m_acc[at][1][r] * wf1;
                part += __shfl_xor(part, 1, 64);
                part += __shfl_xor(part, 2, 64);
                part += __shfl_xor(part, 4, 64);
                part += __shfl_xor(part, 8, 64);
                if (l15 == 0)
                    atomicAdd(&sm_f[at * 16 + (lane >> 4) * 4 + r], part);
            }
        __syncthreads();
        if (t < ETILE) {
            int e = t;
            int d = sm_dst[e];
            if (e == 0 || sm_dst[e - 1] != d) {   // run start
                float fx = 0.f, fy = 0.f, fz = 0.f;
                int j = e;
                do {
                    float f = sm_f[j];
                    fx += f * sm_unit[j][0];
                    fy += f * sm_unit[j][1];
                    fz += f * sm_unit[j][2];
                    j++;
                } while (j < ETILE && sm_dst[j] == d);
                atomicAdd(&outF[d * 3 + 0], fx);
                atomicAdd(&outF[d * 3 + 1], fy);
                atomicAdd(&outF[d * 3 + 2], fz);
            }
        }
    }
}

// ---- Atom-side: h = h0 + sum_i silu(agg_i @ W_upd_i + b_upd_i); out = h @ W_atom + b ----
__global__ void k_atom(const float* __restrict__ agg,
                       const float* __restrict__ W_upd,
                       const float* __restrict__ b_upd,
                       const float* __restrict__ W_atom,
                       const float* __restrict__ b_atom,
                       const ushort_t* __restrict__ h_bf,
                       float* __restrict__ out) {
    int n = blockIdx.x;
    int t = threadIdx.x;  // 0..127
    __shared__ float hrow[HID];
    __shared__ float arow[HID];
    hrow[t] = bf2f(h_bf[n * HID + t]);
    for (int i = 0; i < NBLOCK; i++) {
        arow[t] = agg[(size_t)i * N_ATOMS * HID + n * HID + t];
        __syncthreads();
        float acc = b_upd[i * HID + t];
        const float* Wu = W_upd + (size_t)i * HID * HID;
#pragma unroll 8
        for (int k = 0; k < HID; k++) acc += arow[k] * Wu[k * HID + t];
        __syncthreads();
        hrow[t] += silu(acc);
    }
    __syncthreads();
    if (t < MAXZ) {
        float acc = b_atom[t];
#pragma unroll 8
        for (int k = 0; k < HID; k++) acc += hrow[k] * W_atom[k * MAXZ + t];
        out[N_ATOMS * 3 + n * MAXZ + t] = acc;
    }
}

extern "C" void kernel_launch(void* const* d_in, const int* in_sizes, int n_in,
                              void* d_out, int out_size, void* d_ws, size_t ws_size,
                              hipStream_t stream) {
    const float* z         = (const float*)d_in[0];
    const float* frac      = (const float*)d_in[1];
    const int*   types     = (const int*)d_in[2];
    const float* lengths   = (const float*)d_in[4];
    const float* angles    = (const float*)d_in[5];
    const int*   edge_idx  = (const int*)d_in[6];
    const float* atom_emb  = (const float*)d_in[7];
    const float* W_in      = (const float*)d_in[8];
    const float* b_in      = (const float*)d_in[9];
    const float* W_rbf     = (const float*)d_in[10];
    const float* W_edge    = (const float*)d_in[11];
    const float* b_edge    = (const float*)d_in[12];
    const float* W_msg     = (const float*)d_in[13];
    const float* b_msg     = (const float*)d_in[14];
    const float* W_gate    = (const float*)d_in[15];
    const float* W_upd     = (const float*)d_in[16];
    const float* b_upd     = (const float*)d_in[17];
    const float* W_force   = (const float*)d_in[18];
    const float* W_atom    = (const float*)d_in[19];
    const float* b_atom    = (const float*)d_in[20];

    float* out = (float*)d_out;

    // workspace layout
    float* ws = (float*)d_ws;
    size_t off = 0;
    float* latt = ws + off; off += N_CRYST * 9;
    float* cart = ws + off; off += (size_t)N_ATOMS * 3;
    float* agg  = ws + off; off += (size_t)NBLOCK * N_ATOMS * HID;
    int* cnt    = (int*)(ws + off); off += N_ATOMS;
    int* cursor = (int*)(ws + off); off += N_ATOMS;
    int* perm   = (int*)(ws + off); off += N_EDGES;
    off = (off + 7) & ~(size_t)7;
    ushort_t* ub = (ushort_t*)(ws + off);
    size_t uoff = 0;
    ushort_t* h_bf    = ub + uoff; uoff += (size_t)N_ATOMS * HID;
    ushort_t* Wt_rbf  = ub + uoff; uoff += 128 * 128;
    ushort_t* Wt_edge = ub + uoff; uoff += 128 * 384;
    ushort_t* Wt_msg  = ub + uoff; uoff += 3 * 128 * 128;
    ushort_t* Wt_gate = ub + uoff; uoff += 3 * 128 * 128;

    // zero accumulators + histogram
    {
        int nF = N_ATOMS * 3;
        k_zero<<<(nF + 255) / 256, 256, 0, stream>>>(out, nF);
        int nA = NBLOCK * N_ATOMS * HID;
        k_zero<<<(nA + 255) / 256, 256, 0, stream>>>(agg, nA);
        k_zero_i<<<(N_ATOMS + 255) / 256, 256, 0, stream>>>(cnt, N_ATOMS);
    }

    // counting sort by dst
    k_hist<<<(N_EDGES + 255) / 256, 256, 0, stream>>>(edge_idx, cnt);
    k_scan<<<1, 256, 0, stream>>>(cnt, cursor);
    k_scatter<<<(N_EDGES + 255) / 256, 256, 0, stream>>>(edge_idx, cursor, perm);

    k_latt<<<1, 256, 0, stream>>>(lengths, angles, latt);
    k_cart<<<(N_ATOMS + 255) / 256, 256, 0, stream>>>(frac, latt, cart);
    k_prep<<<192, 256, 0, stream>>>(W_rbf, W_edge, W_msg, W_gate,
                                    Wt_rbf, Wt_edge, Wt_msg, Wt_gate);
    k_h<<<N_ATOMS, HID, 0, stream>>>(types, z, atom_emb, W_in, b_in, h_bf);

    k_edges<<<N_EDGES / ETILE, 256, 0, stream>>>(perm, edge_idx, cart, h_bf,
                                                 Wt_rbf, Wt_edge, b_edge,
                                                 Wt_msg, b_msg, Wt_gate, W_force,
                                                 agg, out);

    k_atom<<<N_ATOMS, HID, 0, stream>>>(agg, W_upd, b_upd, W_atom, b_atom, h_bf, out);
}